// Round 2
// baseline (186.714 us; speedup 1.0000x reference)
//
#include <hip/hip_runtime.h>
#include <hip/hip_bf16.h>
#include <cstddef>

// Problem constants
#define BB 2
#define CC 256
#define HH 64
#define WW 64
#define NN 4096      // H*W
#define NH 8
#define HD 32
#define NLOW 256     // (H/4)*(W/4)
#define KLEN 32      // K_SAMPLES * RATIO^2

typedef __attribute__((ext_vector_type(8))) short short8;
typedef __attribute__((ext_vector_type(4))) float float4v;

__device__ __forceinline__ float b2f(short s) {
    union { unsigned u; float f; } x;
    x.u = ((unsigned)(unsigned short)s) << 16;
    return x.f;
}
__device__ __forceinline__ short f2b(float f) {
    __hip_bfloat16 h = __float2bfloat16(f);  // RNE
    return __builtin_bit_cast(short, h);
}

// ---------------------------------------------------------------------------
// Kernel 1: top-2 per (b, low) row of coarse map -> 32 high-res key indices
// ---------------------------------------------------------------------------
__global__ void topk_kernel(const float* __restrict__ coarse,
                            int* __restrict__ fidx) {
    int t = blockIdx.x * blockDim.x + threadIdx.x;
    if (t >= BB * NLOW) return;
    int b = t / NLOW, low = t % NLOW;
    const float* row = coarse + (size_t)(b * NLOW + low) * NLOW;
    float v1 = -1e30f, v2 = -1e30f;
    int i1 = 0, i2 = 0;
    for (int i = 0; i < NLOW; ++i) {
        float v = row[i];
        if (v > v1)      { v2 = v1; i2 = i1; v1 = v; i1 = i; }
        else if (v > v2) { v2 = v;  i2 = i; }
    }
    int* o = fidx + (size_t)(b * NLOW + low) * KLEN;
    int sel0 = i1, sel1 = i2;
    #pragma unroll
    for (int s = 0; s < 2; ++s) {
        int idx = s == 0 ? sel0 : sel1;
        int r0 = (idx / 16) * 4, c0 = (idx % 16) * 4;
        #pragma unroll
        for (int rr = 0; rr < 4; ++rr)
            #pragma unroll
            for (int cc = 0; cc < 4; ++cc)
                o[s * 16 + rr * 4 + cc] = (r0 + rr) * WW + (c0 + cc);
    }
}

// ---------------------------------------------------------------------------
// Kernel 2: fused q/k/v projections.  A is (B,C,N) channel-major fp32
// (transposed read), W is (C,C) row-major fp32.  Convert to bf16 in LDS,
// 64x64 tile per block, 4 waves x (16x64), MFMA 16x16x32 bf16, fp32 accum,
// bf16 store to workspace.
// ---------------------------------------------------------------------------
#define LDA 48   // LDS row stride in shorts (96 B = 6*16 -> b128-aligned)

__global__ __launch_bounds__(256) void proj_gemm(
    const float* __restrict__ qs, const float* __restrict__ ks,
    const float* __restrict__ vs,
    const float* __restrict__ Wq, const float* __restrict__ bq,
    const float* __restrict__ Wk, const float* __restrict__ bk,
    const float* __restrict__ Wv, const float* __restrict__ bv,
    __hip_bfloat16* __restrict__ qp, __hip_bfloat16* __restrict__ kp,
    __hip_bfloat16* __restrict__ vp)
{
    const int mt  = blockIdx.x;          // 128 tiles of 64 rows (b*N flattened)
    const int nt0 = blockIdx.y * 64;     // output-col tile
    const int which = blockIdx.z;

    const float* src = which == 0 ? qs : which == 1 ? ks : vs;
    const float* W   = which == 0 ? Wq : which == 1 ? Wk : Wv;
    const float* bias = which == 0 ? bq : which == 1 ? bk : bv;
    __hip_bfloat16* outp = which == 0 ? qp : which == 1 ? kp : vp;

    const int b  = mt >> 6;
    const int n0 = (mt & 63) * 64;
    const int t = threadIdx.x;
    const int wave = t >> 6, lane = t & 63;
    const int quad = lane >> 4, l16 = lane & 15;

    __shared__ short As[64 * LDA];   // [m][k]
    __shared__ short Bs[64 * LDA];   // [n][k] (W^T tile)

    float4v acc[4];
    #pragma unroll
    for (int i = 0; i < 4; ++i) acc[i] = (float4v)(0.f);

    const float* srcB = src + (size_t)b * CC * NN;

    for (int k0 = 0; k0 < CC; k0 += 32) {
        __syncthreads();
        {
            const int i  = t & 63;       // row within tile
            const int kb = t >> 6;       // 0..3
            #pragma unroll
            for (int p = 0; p < 8; ++p) {
                int kk = kb + (p << 2);
                As[i * LDA + kk] = f2b(srcB[(size_t)(k0 + kk) * NN + n0 + i]);
                Bs[i * LDA + kk] = f2b(W[(size_t)(k0 + kk) * CC + nt0 + i]);
            }
        }
        __syncthreads();
        short8 af = *(const short8*)&As[(16 * wave + l16) * LDA + quad * 8];
        #pragma unroll
        for (int nt = 0; nt < 4; ++nt) {
            short8 bf = *(const short8*)&Bs[(16 * nt + l16) * LDA + quad * 8];
            acc[nt] = __builtin_amdgcn_mfma_f32_16x16x32_bf16(af, bf, acc[nt], 0, 0, 0);
        }
    }

    #pragma unroll
    for (int nt = 0; nt < 4; ++nt) {
        int col = nt0 + nt * 16 + l16;
        float bv_ = bias[col];
        #pragma unroll
        for (int r = 0; r < 4; ++r) {
            int m_local = 16 * wave + quad * 4 + r;
            outp[(size_t)(b * NN + n0 + m_local) * CC + col] =
                __float2bfloat16(acc[nt][r] + bv_);
        }
    }
}

// ---------------------------------------------------------------------------
// Kernel 3: sparse attention. One block (128 thr) per (b, low):
// 16 queries x 8 heads, 32 shared keys staged in LDS.  bf16 in/out (ws).
// ---------------------------------------------------------------------------
#define KSTR 264   // 264 shorts = 528 B = 33*16 -> b128-aligned rows

__global__ __launch_bounds__(128) void attn_kernel(
    const __hip_bfloat16* __restrict__ qp, const __hip_bfloat16* __restrict__ kp,
    const __hip_bfloat16* __restrict__ vp, const int* __restrict__ fidx,
    __hip_bfloat16* __restrict__ xo)
{
    const int low = blockIdx.x, b = blockIdx.y;
    const int t = threadIdx.x;

    __shared__ short Ks[32 * KSTR];
    __shared__ short Vs[32 * KSTR];
    __shared__ int idx_s[KLEN];

    if (t < KLEN) {
        int idx = fidx[(size_t)(b * NLOW + low) * KLEN + t];
        idx_s[t] = idx < 0 ? 0 : (idx > NN - 1 ? NN - 1 : idx);  // insurance
    }
    __syncthreads();

    const int* kpi = (const int*)kp;
    const int* vpi = (const int*)vp;
    for (int j = 0; j < KLEN; ++j) {
        size_t base = ((size_t)(b * NN + idx_s[j]) * CC) >> 1;  // int units
        ((int*)&Ks[j * KSTR])[t] = kpi[base + t];
        ((int*)&Vs[j * KSTR])[t] = vpi[base + t];
    }
    __syncthreads();

    const int qi = t >> 3, h = t & 7;
    const int n = low * 16 + qi;              // low == n>>4 (repeat semantics)
    const short* qrow = (const short*)qp + (size_t)(b * NN + n) * CC + h * HD;

    float qv[HD];
    #pragma unroll
    for (int c = 0; c < 4; ++c) {
        short8 v = *(const short8*)&qrow[c * 8];
        #pragma unroll
        for (int e = 0; e < 8; ++e) qv[c * 8 + e] = b2f(v[e]);
    }

    const float scale = 0.17677669529663687f;   // 32^-0.5
    float sc[KLEN];
    float mx = -1e30f;
    for (int j = 0; j < KLEN; ++j) {
        const short* kr = &Ks[j * KSTR + h * HD];
        float s = 0.f;
        #pragma unroll
        for (int c = 0; c < 4; ++c) {
            short8 v = *(const short8*)&kr[c * 8];
            #pragma unroll
            for (int e = 0; e < 8; ++e) s += qv[c * 8 + e] * b2f(v[e]);
        }
        s *= scale;
        sc[j] = s;
        mx = fmaxf(mx, s);
    }
    float denom = 0.f;
    #pragma unroll
    for (int j = 0; j < KLEN; ++j) { sc[j] = __expf(sc[j] - mx); denom += sc[j]; }
    const float inv = 1.f / denom;

    float ov[HD];
    #pragma unroll
    for (int d = 0; d < HD; ++d) ov[d] = 0.f;
    for (int j = 0; j < KLEN; ++j) {
        float p = sc[j] * inv;
        const short* vr = &Vs[j * KSTR + h * HD];
        #pragma unroll
        for (int c = 0; c < 4; ++c) {
            short8 v = *(const short8*)&vr[c * 8];
            #pragma unroll
            for (int e = 0; e < 8; ++e) ov[c * 8 + e] += p * b2f(v[e]);
        }
    }

    short* xrow = (short*)xo + (size_t)(b * NN + n) * CC + h * HD;
    #pragma unroll
    for (int c = 0; c < 4; ++c) {
        short8 v;
        #pragma unroll
        for (int e = 0; e < 8; ++e) v[e] = f2b(ov[c * 8 + e]);
        *(short8*)&xrow[c * 8] = v;
    }
}

// ---------------------------------------------------------------------------
// Kernel 4: output projection x @ Wo + bo (x bf16 ws, Wo/bo fp32), store
// fp32 transposed to (B,C,N) through an LDS transpose for coalesced stores.
// ---------------------------------------------------------------------------
__global__ __launch_bounds__(256) void outproj_gemm(
    const __hip_bfloat16* __restrict__ x, const float* __restrict__ Wo,
    const float* __restrict__ bo, float* __restrict__ out)
{
    const int mt  = blockIdx.x;
    const int nt0 = blockIdx.y * 64;
    const int b   = mt >> 6;
    const int n0  = (mt & 63) * 64;
    const int t = threadIdx.x;
    const int wave = t >> 6, lane = t & 63;
    const int quad = lane >> 4, l16 = lane & 15;

    __shared__ short As[64 * LDA];
    __shared__ short Bs[64 * LDA];
    __shared__ float Cs[64 * 65];

    float4v acc[4];
    #pragma unroll
    for (int i = 0; i < 4; ++i) acc[i] = (float4v)(0.f);

    const short* xs = (const short*)x;

    for (int k0 = 0; k0 < CC; k0 += 32) {
        __syncthreads();
        {
            const int i  = t >> 2;           // 0..63
            const int kk = (t & 3) * 8;      // 16B chunk of bf16 x
            *(short8*)&As[i * LDA + kk] =
                *(const short8*)&xs[(size_t)(b * NN + n0 + i) * CC + k0 + kk];
            const int nn = t & 63;
            const int kb = t >> 6;
            #pragma unroll
            for (int p = 0; p < 8; ++p) {
                int kk2 = kb + (p << 2);
                Bs[nn * LDA + kk2] = f2b(Wo[(size_t)(k0 + kk2) * CC + nt0 + nn]);
            }
        }
        __syncthreads();
        short8 af = *(const short8*)&As[(16 * wave + l16) * LDA + quad * 8];
        #pragma unroll
        for (int nt = 0; nt < 4; ++nt) {
            short8 bf = *(const short8*)&Bs[(16 * nt + l16) * LDA + quad * 8];
            acc[nt] = __builtin_amdgcn_mfma_f32_16x16x32_bf16(af, bf, acc[nt], 0, 0, 0);
        }
    }

    __syncthreads();
    #pragma unroll
    for (int nt = 0; nt < 4; ++nt) {
        int col = nt0 + nt * 16 + l16;
        float bias = bo[col];
        #pragma unroll
        for (int r = 0; r < 4; ++r) {
            int m_local = 16 * wave + quad * 4 + r;
            Cs[m_local * 65 + nt * 16 + l16] = acc[nt][r] + bias;
        }
    }
    __syncthreads();
    // out[b][c][n]: c = nt0 + cl, n = n0 + nl (fp32 coalesced over nl)
    #pragma unroll
    for (int p = 0; p < 16; ++p) {
        int cl = (t >> 6) + 4 * p;
        int nl = t & 63;
        out[(size_t)(b * CC + nt0 + cl) * NN + n0 + nl] = Cs[nl * 65 + cl];
    }
}

// ---------------------------------------------------------------------------
extern "C" void kernel_launch(void* const* d_in, const int* in_sizes, int n_in,
                              void* d_out, int out_size, void* d_ws, size_t ws_size,
                              hipStream_t stream) {
    const float* q      = (const float*)d_in[0];
    const float* k      = (const float*)d_in[1];
    const float* v      = (const float*)d_in[2];
    const float* coarse = (const float*)d_in[3];
    const float* Wq     = (const float*)d_in[4];
    const float* bq     = (const float*)d_in[5];
    const float* Wk     = (const float*)d_in[6];
    const float* bk     = (const float*)d_in[7];
    const float* Wv     = (const float*)d_in[8];
    const float* bv     = (const float*)d_in[9];
    const float* Wo     = (const float*)d_in[10];
    const float* bo     = (const float*)d_in[11];

    char* ws = (char*)d_ws;
    const size_t PROJ_BYTES = (size_t)BB * NN * CC * 2;   // 4 MiB each (bf16)
    __hip_bfloat16* qp = (__hip_bfloat16*)(ws);
    __hip_bfloat16* kp = (__hip_bfloat16*)(ws + PROJ_BYTES);
    __hip_bfloat16* vp = (__hip_bfloat16*)(ws + 2 * PROJ_BYTES);
    __hip_bfloat16* xo = (__hip_bfloat16*)(ws + 3 * PROJ_BYTES);
    int* fidx          = (int*)(ws + 4 * PROJ_BYTES);

    topk_kernel<<<2, 256, 0, stream>>>(coarse, fidx);
    proj_gemm<<<dim3(128, 4, 3), 256, 0, stream>>>(q, k, v, Wq, bq, Wk, bk,
                                                   Wv, bv, qp, kp, vp);
    attn_kernel<<<dim3(NLOW, BB), 128, 0, stream>>>(qp, kp, vp, fidx, xo);
    outproj_gemm<<<dim3(128, 4), 256, 0, stream>>>(xo, Wo, bo, (float*)d_out);
}

// Round 4
// 129.856 us; speedup vs baseline: 1.4379x; 1.4379x over previous
//
#include <hip/hip_runtime.h>
#include <hip/hip_bf16.h>
#include <cstddef>

#define BB 2
#define CC 256
#define HH 64
#define WW 64
#define NN 4096      // H*W
#define NH 8
#define HD 32
#define NLOW 256     // (H/4)*(W/4)
#define KLEN 32      // K_SAMPLES * RATIO^2

typedef __attribute__((ext_vector_type(8))) short short8;
typedef __attribute__((ext_vector_type(4))) float float4v;

__device__ __forceinline__ float b2f(short s) {
    union { unsigned u; float f; } x;
    x.u = ((unsigned)(unsigned short)s) << 16;
    return x.f;
}
__device__ __forceinline__ short f2b(float f) {
    __hip_bfloat16 h = __float2bfloat16(f);  // RNE
    return __builtin_bit_cast(short, h);
}

// ---------------------------------------------------------------------------
// Kernel 1: top-2 per (b,low) row: one wave per row, butterfly top-2 reduce.
// Tie-break = lowest index (matches lax.top_k first-occurrence).
// ---------------------------------------------------------------------------
__global__ __launch_bounds__(256) void topk_kernel(const float* __restrict__ coarse,
                                                   int* __restrict__ fidx) {
    const int w = threadIdx.x >> 6, l = threadIdx.x & 63;
    const int row = blockIdx.x * 4 + w;                 // 0..511 = b*NLOW+low
    const float* r = coarse + (size_t)row * NLOW;
    float4v x = *(const float4v*)&r[l * 4];
    const int base = l * 4;
    float v1 = x[0]; int i1 = base;
    float v2 = x[1]; int i2 = base + 1;
    if (v2 > v1) { float tv = v1; v1 = v2; v2 = tv; int ti = i1; i1 = i2; i2 = ti; }
    #pragma unroll
    for (int j = 2; j < 4; ++j) {
        float e = x[j]; int ei = base + j;
        if (e > v1)      { v2 = v1; i2 = i1; v1 = e; i1 = ei; }
        else if (e > v2) { v2 = e;  i2 = ei; }
    }
    #pragma unroll
    for (int off = 1; off < 64; off <<= 1) {
        float ov1 = __shfl_xor(v1, off), ov2 = __shfl_xor(v2, off);
        int   oi1 = __shfl_xor(i1, off), oi2 = __shfl_xor(i2, off);
        bool aw = (v1 > ov1) || (v1 == ov1 && i1 < oi1);
        float nv1 = aw ? v1 : ov1;  int ni1 = aw ? i1 : oi1;
        float c1v = aw ? ov1 : v1;  int c1i = aw ? oi1 : i1;   // loser of firsts
        float c2v = aw ? v2 : ov2;  int c2i = aw ? i2 : oi2;   // winner's 2nd
        bool bw = (c1v > c2v) || (c1v == c2v && c1i < c2i);
        v1 = nv1; i1 = ni1;
        v2 = bw ? c1v : c2v; i2 = bw ? c1i : c2i;
    }
    if (l < 32) {
        int s = l >> 4, jj = l & 15;
        int idx = s ? i2 : i1;
        int rr = jj >> 2, cc2 = jj & 3;
        fidx[(size_t)row * KLEN + l] =
            ((idx >> 4) * 4 + rr) * WW + (idx & 15) * 4 + cc2;
    }
}

// ---------------------------------------------------------------------------
// Tiled 64x64 transpose: src fp32 (rows x cols, ld=sld) -> dst bf16
// (cols x rows, ld=dld).  Padded LDS (65) -> conflict-free-ish both phases.
// ---------------------------------------------------------------------------
__device__ __forceinline__ void trans_tile(const float* __restrict__ src, size_t soff,
                                           int sld, short* __restrict__ dst,
                                           size_t doff, int dld) {
    __shared__ float tile[64 * 65];
    const int t = threadIdx.x;
    #pragma unroll
    for (int p = 0; p < 4; ++p) {
        int r  = p * 16 + (t >> 4);
        int c4 = (t & 15) * 4;
        float4v v = *(const float4v*)&src[soff + (size_t)r * sld + c4];
        tile[r * 65 + c4 + 0] = v[0];
        tile[r * 65 + c4 + 1] = v[1];
        tile[r * 65 + c4 + 2] = v[2];
        tile[r * 65 + c4 + 3] = v[3];
    }
    __syncthreads();
    #pragma unroll
    for (int p = 0; p < 2; ++p) {
        int n  = p * 32 + (t >> 3);      // dst row (src col)
        int c0 = (t & 7) * 8;            // dst col chunk (src rows)
        short8 o;
        #pragma unroll
        for (int j = 0; j < 8; ++j) o[j] = f2b(tile[(c0 + j) * 65 + n]);
        *(short8*)&dst[doff + (size_t)n * dld + c0] = o;
    }
}

__global__ __launch_bounds__(256) void transpose_feat(
    const float* __restrict__ q, const float* __restrict__ k,
    const float* __restrict__ v, short* __restrict__ qt,
    short* __restrict__ kt, short* __restrict__ vt) {
    const int z = blockIdx.z;                     // 0..5
    const float* src = (z < 2) ? q : (z < 4) ? k : v;
    short* dst       = (z < 2) ? qt : (z < 4) ? kt : vt;
    const int b = z & 1;
    const int n0 = blockIdx.x * 64, c0 = blockIdx.y * 64;
    trans_tile(src, (size_t)b * CC * NN + (size_t)c0 * NN + n0, NN,
               dst, ((size_t)b * NN + n0) * CC + c0, CC);
}

__global__ __launch_bounds__(256) void transpose_w(
    const float* __restrict__ Wq, const float* __restrict__ Wk,
    const float* __restrict__ Wv, const float* __restrict__ Wo,
    short* __restrict__ Wt) {
    const int z = blockIdx.z;                     // 0..3: q,k,v,o
    const float* src = (z == 0) ? Wq : (z == 1) ? Wk : (z == 2) ? Wv : Wo;
    short* dst = Wt + (size_t)z * CC * CC;
    const int co0 = blockIdx.x * 64, ci0 = blockIdx.y * 64;
    trans_tile(src, (size_t)ci0 * CC + co0, CC,
               dst, (size_t)co0 * CC + ci0, CC);
}

// ---------------------------------------------------------------------------
// GEMM core: A (rows x 256 bf16 row-major), Bt (c_out x 256 bf16 row-major),
// 64x64 tile, BK=64.  XOR-swizzled LDS chunks: element (m, chunk c) lives at
// physical chunk m*8 + (c ^ (m&7)).  Writes are lane-ordered (bank-balanced);
// MFMA b128 reads land 2 lanes/bank (free).
// ---------------------------------------------------------------------------
__device__ __forceinline__ void gemm_core_64x64(
    const short* __restrict__ A, int am0, const short* __restrict__ Bt, int bn0,
    short* As, short* Bs, float4v acc[4]) {
    const int t = threadIdx.x;
    const int w = t >> 6, lane = t & 63;
    const int l16 = lane & 15, quad = lane >> 4;
    for (int k0 = 0; k0 < CC; k0 += 64) {
        __syncthreads();
        #pragma unroll
        for (int g = 0; g < 2; ++g) {
            int p = (w * 2 + g) * 64 + lane;          // physical chunk 0..511
            int m = p >> 3;
            int cl8 = (((p & 7) ^ (m & 7)) << 3);     // logical k-offset (elems)
            short8 av = *(const short8*)(A  + (size_t)(am0 + m) * CC + k0 + cl8);
            short8 bv = *(const short8*)(Bt + (size_t)(bn0 + m) * CC + k0 + cl8);
            *(short8*)((char*)As + (size_t)p * 16) = av;
            *(short8*)((char*)Bs + (size_t)p * 16) = bv;
        }
        __syncthreads();
        #pragma unroll
        for (int s = 0; s < 2; ++s) {
            const int Ra = 16 * w + l16;
            short8 af = *(const short8*)((const char*)As + Ra * 128 +
                                         (((s * 4 + quad) ^ (Ra & 7)) << 4));
            #pragma unroll
            for (int nt = 0; nt < 4; ++nt) {
                const int Rb = nt * 16 + l16;
                short8 bf = *(const short8*)((const char*)Bs + Rb * 128 +
                                             (((s * 4 + quad) ^ (Rb & 7)) << 4));
                acc[nt] = __builtin_amdgcn_mfma_f32_16x16x32_bf16(af, bf, acc[nt], 0, 0, 0);
            }
        }
    }
}

// Kernel 3: fused q/k/v projections (bf16 in, bf16 out, row-major)
__global__ __launch_bounds__(256) void proj_gemm(
    const short* __restrict__ qt, const short* __restrict__ kt,
    const short* __restrict__ vt, const short* __restrict__ Wt,
    const float* __restrict__ bq, const float* __restrict__ bk,
    const float* __restrict__ bv,
    short* __restrict__ qp, short* __restrict__ kp, short* __restrict__ vp) {
    const int which = blockIdx.z;
    const short* A  = which == 0 ? qt : which == 1 ? kt : vt;
    const short* B  = Wt + (size_t)which * CC * CC;
    const float* bias = which == 0 ? bq : which == 1 ? bk : bv;
    short* outp     = which == 0 ? qp : which == 1 ? kp : vp;
    const int am0 = blockIdx.x * 64;        // row tile in (B*N) space
    const int nt0 = blockIdx.y * 64;

    __shared__ short As[64 * 64];
    __shared__ short Bs[64 * 64];
    float4v acc[4];
    #pragma unroll
    for (int i = 0; i < 4; ++i) acc[i] = (float4v)(0.f);

    gemm_core_64x64(A, am0, B, nt0, As, Bs, acc);

    const int t = threadIdx.x;
    const int w = t >> 6, lane = t & 63;
    const int l16 = lane & 15, quad = lane >> 4;
    #pragma unroll
    for (int nt = 0; nt < 4; ++nt) {
        int col = nt0 + nt * 16 + l16;
        float bv_ = bias[col];
        #pragma unroll
        for (int r = 0; r < 4; ++r) {
            int m = am0 + 16 * w + quad * 4 + r;
            outp[(size_t)m * CC + col] = f2b(acc[nt][r] + bv_);
        }
    }
}

// ---------------------------------------------------------------------------
// Kernel 4: sparse attention.  256 thr/block per (b,low): thread =
// (query qi, head h, half-dim dh).  32 keys staged in LDS (broadcast reads).
// ---------------------------------------------------------------------------
#define KSTR 264   // shorts; 528 B rows (16B aligned)

__global__ __launch_bounds__(256) void attn_kernel(
    const short* __restrict__ qp, const short* __restrict__ kp,
    const short* __restrict__ vp, const int* __restrict__ fidx,
    short* __restrict__ xo) {
    const int low = blockIdx.x, b = blockIdx.y;
    const int t = threadIdx.x;

    __shared__ short Ks[32 * KSTR];
    __shared__ short Vs[32 * KSTR];
    __shared__ int idx_s[KLEN];

    if (t < KLEN) {
        int idx = fidx[(size_t)(b * NLOW + low) * KLEN + t];
        idx_s[t] = idx < 0 ? 0 : (idx > NN - 1 ? NN - 1 : idx);
    }
    __syncthreads();

    const int* kpi = (const int*)kp;
    const int* vpi = (const int*)vp;
    const int half = t >> 7, col = t & 127;
    for (int j = 0; j < KLEN; j += 2) {
        int key = j + half;
        size_t base = (size_t)(b * NN + idx_s[key]) * (CC / 2);
        ((int*)&Ks[key * KSTR])[col] = kpi[base + col];
        ((int*)&Vs[key * KSTR])[col] = vpi[base + col];
    }
    __syncthreads();

    const int qi = t >> 4, h = (t >> 1) & 7, dh = t & 1;
    const int n = low * 16 + qi;             // low == n>>4 (repeat semantics)
    const short* qrow = qp + (size_t)(b * NN + n) * CC + h * HD;

    float qv[HD];
    #pragma unroll
    for (int c = 0; c < 4; ++c) {
        short8 v = *(const short8*)&qrow[c * 8];
        #pragma unroll
        for (int e = 0; e < 8; ++e) qv[c * 8 + e] = b2f(v[e]);
    }

    const float scale = 0.17677669529663687f;   // 32^-0.5
    float sc[KLEN];
    float mx = -1e30f;
    for (int j = 0; j < KLEN; ++j) {
        const short* kr = &Ks[j * KSTR + h * HD];
        float s = 0.f;
        #pragma unroll
        for (int c = 0; c < 4; ++c) {
            short8 v = *(const short8*)&kr[c * 8];
            #pragma unroll
            for (int e = 0; e < 8; ++e) s += qv[c * 8 + e] * b2f(v[e]);
        }
        s *= scale;
        sc[j] = s;
        mx = fmaxf(mx, s);
    }
    float denom = 0.f;
    #pragma unroll
    for (int j = 0; j < KLEN; ++j) { sc[j] = __expf(sc[j] - mx); denom += sc[j]; }
    const float inv = 1.f / denom;

    float ov[16];
    #pragma unroll
    for (int d = 0; d < 16; ++d) ov[d] = 0.f;
    for (int j = 0; j < KLEN; ++j) {
        float p = sc[j] * inv;
        const short* vr = &Vs[j * KSTR + h * HD + dh * 16];
        #pragma unroll
        for (int c = 0; c < 2; ++c) {
            short8 v = *(const short8*)&vr[c * 8];
            #pragma unroll
            for (int e = 0; e < 8; ++e) ov[c * 8 + e] += p * b2f(v[e]);
        }
    }

    short* xrow = xo + (size_t)(b * NN + n) * CC + h * HD + dh * 16;
    #pragma unroll
    for (int c = 0; c < 2; ++c) {
        short8 v;
        #pragma unroll
        for (int e = 0; e < 8; ++e) v[e] = f2b(ov[c * 8 + e]);
        *(short8*)&xrow[c * 8] = v;
    }
}

// ---------------------------------------------------------------------------
// Kernel 5: output projection, fp32 (B,C,N) output via LDS transpose.
// ---------------------------------------------------------------------------
__global__ __launch_bounds__(256) void outproj_gemm(
    const short* __restrict__ x, const short* __restrict__ Wto,
    const float* __restrict__ bo, float* __restrict__ out) {
    const int mt  = blockIdx.x;
    const int am0 = mt * 64;
    const int nt0 = blockIdx.y * 64;
    const int b   = mt >> 6;
    const int n0  = (mt & 63) * 64;

    __shared__ short As[64 * 64];
    __shared__ short Bs[64 * 64];
    __shared__ float Cs[64 * 65];

    float4v acc[4];
    #pragma unroll
    for (int i = 0; i < 4; ++i) acc[i] = (float4v)(0.f);

    gemm_core_64x64(x, am0, Wto, nt0, As, Bs, acc);

    const int t = threadIdx.x;
    const int w = t >> 6, lane = t & 63;
    const int l16 = lane & 15, quad = lane >> 4;
    __syncthreads();
    #pragma unroll
    for (int nt = 0; nt < 4; ++nt) {
        float bias = bo[nt0 + nt * 16 + l16];
        #pragma unroll
        for (int r = 0; r < 4; ++r) {
            int m = 16 * w + quad * 4 + r;
            Cs[m * 65 + nt * 16 + l16] = acc[nt][r] + bias;
        }
    }
    __syncthreads();
    #pragma unroll
    for (int p = 0; p < 16; ++p) {
        int cl = (t >> 6) + 4 * p;
        int nl = t & 63;
        out[(size_t)(b * CC + nt0 + cl) * NN + n0 + nl] = Cs[nl * 65 + cl];
    }
}

// ---------------------------------------------------------------------------
extern "C" void kernel_launch(void* const* d_in, const int* in_sizes, int n_in,
                              void* d_out, int out_size, void* d_ws, size_t ws_size,
                              hipStream_t stream) {
    const float* q      = (const float*)d_in[0];
    const float* k      = (const float*)d_in[1];
    const float* v      = (const float*)d_in[2];
    const float* coarse = (const float*)d_in[3];
    const float* Wq     = (const float*)d_in[4];
    const float* bq     = (const float*)d_in[5];
    const float* Wk     = (const float*)d_in[6];
    const float* bk     = (const float*)d_in[7];
    const float* Wv     = (const float*)d_in[8];
    const float* bv     = (const float*)d_in[9];
    const float* Wo     = (const float*)d_in[10];
    const float* bo     = (const float*)d_in[11];

    char* ws = (char*)d_ws;
    const size_t MB4 = (size_t)BB * NN * CC * 2;     // 4 MiB (bf16 B*N*C)
    short* qt = (short*)(ws);                        // dead after proj -> xo
    short* kt = (short*)(ws + MB4);
    short* vt = (short*)(ws + 2 * MB4);
    short* qp = (short*)(ws + 3 * MB4);
    short* kp = (short*)(ws + 4 * MB4);
    short* vp = (short*)(ws + 5 * MB4);
    short* Wt = (short*)(ws + 6 * MB4);              // 4 x 128 KiB
    int* fidx = (int*)(ws + 6 * MB4 + 4 * (size_t)CC * CC * 2);
    short* xo = qt;                                  // alias (qt dead by then)

    topk_kernel<<<128, 256, 0, stream>>>(coarse, fidx);
    transpose_feat<<<dim3(64, 4, 6), 256, 0, stream>>>(q, k, v, qt, kt, vt);
    transpose_w<<<dim3(4, 4, 4), 256, 0, stream>>>(Wq, Wk, Wv, Wo, Wt);
    proj_gemm<<<dim3(128, 4, 3), 256, 0, stream>>>(qt, kt, vt, Wt, bq, bk, bv,
                                                   qp, kp, vp);
    attn_kernel<<<dim3(NLOW, BB), 256, 0, stream>>>(qp, kp, vp, fidx, xo);
    outproj_gemm<<<dim3(128, 4), 256, 0, stream>>>(xo, Wt + 3 * CC * CC, bo,
                                                   (float*)d_out);
}

// Round 5
// 125.085 us; speedup vs baseline: 1.4927x; 1.0381x over previous
//
#include <hip/hip_runtime.h>
#include <hip/hip_bf16.h>
#include <cstddef>

#define BB 2
#define CC 256
#define HH 64
#define WW 64
#define NN 4096      // H*W
#define NH 8
#define HD 32
#define NLOW 256     // (H/4)*(W/4)
#define KLEN 32      // K_SAMPLES * RATIO^2

typedef __attribute__((ext_vector_type(8))) short short8;
typedef __attribute__((ext_vector_type(4))) float float4v;

__device__ __forceinline__ float b2f(short s) {
    union { unsigned u; float f; } x;
    x.u = ((unsigned)(unsigned short)s) << 16;
    return x.f;
}
__device__ __forceinline__ short f2b(float f) {
    __hip_bfloat16 h = __float2bfloat16(f);  // RNE
    return __builtin_bit_cast(short, h);
}

// ---------------------------------------------------------------------------
// Prep kernel: z<6 -> feature transpose tiles; z==6 -> weight transposes (64
// jobs) + top-2 reduction (128 jobs).  One launch instead of three.
// ---------------------------------------------------------------------------
__device__ __forceinline__ void trans_tile(const float* __restrict__ src, size_t soff,
                                           int sld, short* __restrict__ dst,
                                           size_t doff, int dld) {
    __shared__ float tile[64 * 65];
    const int t = threadIdx.x;
    #pragma unroll
    for (int p = 0; p < 4; ++p) {
        int r  = p * 16 + (t >> 4);
        int c4 = (t & 15) * 4;
        float4v v = *(const float4v*)&src[soff + (size_t)r * sld + c4];
        tile[r * 65 + c4 + 0] = v[0];
        tile[r * 65 + c4 + 1] = v[1];
        tile[r * 65 + c4 + 2] = v[2];
        tile[r * 65 + c4 + 3] = v[3];
    }
    __syncthreads();
    #pragma unroll
    for (int p = 0; p < 2; ++p) {
        int n  = p * 32 + (t >> 3);      // dst row (src col)
        int c0 = (t & 7) * 8;            // dst col chunk (src rows)
        short8 o;
        #pragma unroll
        for (int j = 0; j < 8; ++j) o[j] = f2b(tile[(c0 + j) * 65 + n]);
        *(short8*)&dst[doff + (size_t)n * dld + c0] = o;
    }
}

__global__ __launch_bounds__(256) void prep_kernel(
    const float* __restrict__ q, const float* __restrict__ k,
    const float* __restrict__ v, const float* __restrict__ Wq,
    const float* __restrict__ Wk, const float* __restrict__ Wv,
    const float* __restrict__ Wo, const float* __restrict__ coarse,
    short* __restrict__ qt, short* __restrict__ kt, short* __restrict__ vt,
    short* __restrict__ Wt, int* __restrict__ fidx) {
    const int z = blockIdx.z;
    if (z < 6) {                                   // feature transposes
        const float* src = (z < 2) ? q : (z < 4) ? k : v;
        short* dst       = (z < 2) ? qt : (z < 4) ? kt : vt;
        const int b = z & 1;
        const int n0 = blockIdx.x * 64, c0 = blockIdx.y * 64;
        trans_tile(src, (size_t)b * CC * NN + (size_t)c0 * NN + n0, NN,
                   dst, ((size_t)b * NN + n0) * CC + c0, CC);
        return;
    }
    const int id = blockIdx.y * 64 + blockIdx.x;   // 0..255
    if (id < 64) {                                 // weight transposes
        const int wz = id >> 4, tile = id & 15;
        const float* src = (wz == 0) ? Wq : (wz == 1) ? Wk : (wz == 2) ? Wv : Wo;
        short* dst = Wt + (size_t)wz * CC * CC;
        const int co0 = (tile >> 2) * 64, ci0 = (tile & 3) * 64;
        trans_tile(src, (size_t)ci0 * CC + co0, CC,
                   dst, (size_t)co0 * CC + ci0, CC);
        return;
    }
    if (id >= 192) return;
    // top-2: 4 rows per block, one wave per row
    const int w = threadIdx.x >> 6, l = threadIdx.x & 63;
    const int row = (id - 64) * 4 + w;             // 0..511 = b*NLOW+low
    const float* r = coarse + (size_t)row * NLOW;
    float4v x = *(const float4v*)&r[l * 4];
    const int base = l * 4;
    float v1 = x[0]; int i1 = base;
    float v2 = x[1]; int i2 = base + 1;
    if (v2 > v1) { float tv = v1; v1 = v2; v2 = tv; int ti = i1; i1 = i2; i2 = ti; }
    #pragma unroll
    for (int j = 2; j < 4; ++j) {
        float e = x[j]; int ei = base + j;
        if (e > v1)      { v2 = v1; i2 = i1; v1 = e; i1 = ei; }
        else if (e > v2) { v2 = e;  i2 = ei; }
    }
    #pragma unroll
    for (int off = 1; off < 64; off <<= 1) {
        float ov1 = __shfl_xor(v1, off), ov2 = __shfl_xor(v2, off);
        int   oi1 = __shfl_xor(i1, off), oi2 = __shfl_xor(i2, off);
        bool aw = (v1 > ov1) || (v1 == ov1 && i1 < oi1);
        float nv1 = aw ? v1 : ov1;  int ni1 = aw ? i1 : oi1;
        float c1v = aw ? ov1 : v1;  int c1i = aw ? oi1 : i1;   // loser of firsts
        float c2v = aw ? v2 : ov2;  int c2i = aw ? i2 : oi2;   // winner's 2nd
        bool bw = (c1v > c2v) || (c1v == c2v && c1i < c2i);
        v1 = nv1; i1 = ni1;
        v2 = bw ? c1v : c2v; i2 = bw ? c1i : c2i;
    }
    if (l < 32) {
        int s = l >> 4, jj = l & 15;
        int idx = s ? i2 : i1;
        int rr = jj >> 2, cc2 = jj & 3;
        fidx[(size_t)row * KLEN + l] =
            ((idx >> 4) * 4 + rr) * WW + (idx & 15) * 4 + cc2;
    }
}

// ---------------------------------------------------------------------------
// GEMM core, MT m-subtiles of 64 (tile = 64*MT x 64), BK=64.  XOR-swizzled
// LDS chunks: logical (m, chunk c) at physical chunk m*8 + (c ^ (m&7)).
// ---------------------------------------------------------------------------
template <int MT>
__device__ __forceinline__ void gemm_core(
    const short* __restrict__ A, int am0, const short* __restrict__ Bt, int bn0,
    short* As, short* Bs, float4v acc[MT][4]) {
    const int t = threadIdx.x;
    const int w = t >> 6, lane = t & 63;
    const int l16 = lane & 15, quad = lane >> 4;
    for (int k0 = 0; k0 < CC; k0 += 64) {
        __syncthreads();
        #pragma unroll
        for (int g = 0; g < 2 * MT; ++g) {
            int p = (w * 2 * MT + g) * 64 + lane;     // physical chunk
            int m = p >> 3;
            int cl8 = (((p & 7) ^ (m & 7)) << 3);     // logical k-offset (elems)
            *(short8*)((char*)As + (size_t)p * 16) =
                *(const short8*)(A + (size_t)(am0 + m) * CC + k0 + cl8);
        }
        #pragma unroll
        for (int g = 0; g < 2; ++g) {
            int p = (w * 2 + g) * 64 + lane;
            int m = p >> 3;
            int cl8 = (((p & 7) ^ (m & 7)) << 3);
            *(short8*)((char*)Bs + (size_t)p * 16) =
                *(const short8*)(Bt + (size_t)(bn0 + m) * CC + k0 + cl8);
        }
        __syncthreads();
        #pragma unroll
        for (int s = 0; s < 2; ++s) {
            short8 bf[4];
            #pragma unroll
            for (int nt = 0; nt < 4; ++nt) {
                const int Rb = nt * 16 + l16;
                bf[nt] = *(const short8*)((const char*)Bs + Rb * 128 +
                                          (((s * 4 + quad) ^ (Rb & 7)) << 4));
            }
            #pragma unroll
            for (int mt = 0; mt < MT; ++mt) {
                const int Ra = mt * 64 + 16 * w + l16;
                short8 af = *(const short8*)((const char*)As + Ra * 128 +
                                             (((s * 4 + quad) ^ (Ra & 7)) << 4));
                #pragma unroll
                for (int nt = 0; nt < 4; ++nt)
                    acc[mt][nt] = __builtin_amdgcn_mfma_f32_16x16x32_bf16(
                        af, bf[nt], acc[mt][nt], 0, 0, 0);
            }
        }
    }
}

// Kernel: fused q/k/v projections, 128x64 tiles (bf16 in/out row-major)
__global__ __launch_bounds__(256) void proj_gemm(
    const short* __restrict__ qt, const short* __restrict__ kt,
    const short* __restrict__ vt, const short* __restrict__ Wt,
    const float* __restrict__ bq, const float* __restrict__ bk,
    const float* __restrict__ bv,
    short* __restrict__ qp, short* __restrict__ kp, short* __restrict__ vp) {
    const int which = blockIdx.z;
    const short* A  = which == 0 ? qt : which == 1 ? kt : vt;
    const short* B  = Wt + (size_t)which * CC * CC;
    const float* bias = which == 0 ? bq : which == 1 ? bk : bv;
    short* outp     = which == 0 ? qp : which == 1 ? kp : vp;
    const int am0 = blockIdx.x * 128;       // row tile in (B*N) space
    const int nt0 = blockIdx.y * 64;

    __shared__ short As[128 * 64];
    __shared__ short Bs[64 * 64];
    float4v acc[2][4];
    #pragma unroll
    for (int i = 0; i < 2; ++i)
        #pragma unroll
        for (int j = 0; j < 4; ++j) acc[i][j] = (float4v)(0.f);

    gemm_core<2>(A, am0, B, nt0, As, Bs, acc);

    const int t = threadIdx.x;
    const int w = t >> 6, lane = t & 63;
    const int l16 = lane & 15, quad = lane >> 4;
    #pragma unroll
    for (int mt = 0; mt < 2; ++mt)
        #pragma unroll
        for (int nt = 0; nt < 4; ++nt) {
            int col = nt0 + nt * 16 + l16;
            float bv_ = bias[col];
            #pragma unroll
            for (int r = 0; r < 4; ++r) {
                int m = am0 + mt * 64 + 16 * w + quad * 4 + r;
                outp[(size_t)m * CC + col] = f2b(acc[mt][nt][r] + bv_);
            }
        }
}

// ---------------------------------------------------------------------------
// Sparse attention.  256 thr/block per (b,low): thread = (qi, h, dh).
// Each dh-half computes a 16-dim partial dot; combined via shfl_xor(1).
// ---------------------------------------------------------------------------
#define KSTR 264   // shorts; 528 B rows (16B aligned)

__global__ __launch_bounds__(256) void attn_kernel(
    const short* __restrict__ qp, const short* __restrict__ kp,
    const short* __restrict__ vp, const int* __restrict__ fidx,
    short* __restrict__ xo) {
    const int low = blockIdx.x, b = blockIdx.y;
    const int t = threadIdx.x;

    __shared__ short Ks[32 * KSTR];
    __shared__ short Vs[32 * KSTR];
    __shared__ int idx_s[KLEN];

    if (t < KLEN) {
        int idx = fidx[(size_t)(b * NLOW + low) * KLEN + t];
        idx_s[t] = idx < 0 ? 0 : (idx > NN - 1 ? NN - 1 : idx);
    }
    __syncthreads();

    const int* kpi = (const int*)kp;
    const int* vpi = (const int*)vp;
    const int half = t >> 7, col = t & 127;
    for (int j = 0; j < KLEN; j += 2) {
        int key = j + half;
        size_t base = (size_t)(b * NN + idx_s[key]) * (CC / 2);
        ((int*)&Ks[key * KSTR])[col] = kpi[base + col];
        ((int*)&Vs[key * KSTR])[col] = vpi[base + col];
    }
    __syncthreads();

    const int qi = t >> 4, h = (t >> 1) & 7, dh = t & 1;
    const int n = low * 16 + qi;             // low == n>>4 (repeat semantics)
    const short* qrow = qp + (size_t)(b * NN + n) * CC + h * HD + dh * 16;

    float qv[16];
    #pragma unroll
    for (int c = 0; c < 2; ++c) {
        short8 v = *(const short8*)&qrow[c * 8];
        #pragma unroll
        for (int e = 0; e < 8; ++e) qv[c * 8 + e] = b2f(v[e]);
    }

    const float scale = 0.17677669529663687f;   // 32^-0.5
    float sc[KLEN];
    for (int j = 0; j < KLEN; ++j) {
        const short* kr = &Ks[j * KSTR + h * HD + dh * 16];
        float s = 0.f;
        #pragma unroll
        for (int c = 0; c < 2; ++c) {
            short8 v = *(const short8*)&kr[c * 8];
            #pragma unroll
            for (int e = 0; e < 8; ++e) s += qv[c * 8 + e] * b2f(v[e]);
        }
        sc[j] = s;
    }
    float mx = -1e30f;
    #pragma unroll
    for (int j = 0; j < KLEN; ++j) {
        sc[j] = (sc[j] + __shfl_xor(sc[j], 1)) * scale;   // combine halves
        mx = fmaxf(mx, sc[j]);
    }
    float denom = 0.f;
    #pragma unroll
    for (int j = 0; j < KLEN; ++j) { sc[j] = __expf(sc[j] - mx); denom += sc[j]; }
    const float inv = 1.f / denom;

    float ov[16];
    #pragma unroll
    for (int d = 0; d < 16; ++d) ov[d] = 0.f;
    for (int j = 0; j < KLEN; ++j) {
        float p = sc[j] * inv;
        const short* vr = &Vs[j * KSTR + h * HD + dh * 16];
        #pragma unroll
        for (int c = 0; c < 2; ++c) {
            short8 v = *(const short8*)&vr[c * 8];
            #pragma unroll
            for (int e = 0; e < 8; ++e) ov[c * 8 + e] += p * b2f(v[e]);
        }
    }

    short* xrow = xo + (size_t)(b * NN + n) * CC + h * HD + dh * 16;
    #pragma unroll
    for (int c = 0; c < 2; ++c) {
        short8 v;
        #pragma unroll
        for (int e = 0; e < 8; ++e) v[e] = f2b(ov[c * 8 + e]);
        *(short8*)&xrow[c * 8] = v;
    }
}

// ---------------------------------------------------------------------------
// Output projection, 64x64 tiles, fp32 (B,C,N) output via LDS transpose.
// ---------------------------------------------------------------------------
__global__ __launch_bounds__(256) void outproj_gemm(
    const short* __restrict__ x, const short* __restrict__ Wto,
    const float* __restrict__ bo, float* __restrict__ out) {
    const int mt  = blockIdx.x;
    const int am0 = mt * 64;
    const int nt0 = blockIdx.y * 64;
    const int b   = mt >> 6;
    const int n0  = (mt & 63) * 64;

    __shared__ short As[64 * 64];
    __shared__ short Bs[64 * 64];
    __shared__ float Cs[64 * 65];

    float4v acc[1][4];
    #pragma unroll
    for (int j = 0; j < 4; ++j) acc[0][j] = (float4v)(0.f);

    gemm_core<1>(x, am0, Wto, nt0, As, Bs, acc);

    const int t = threadIdx.x;
    const int w = t >> 6, lane = t & 63;
    const int l16 = lane & 15, quad = lane >> 4;
    __syncthreads();
    #pragma unroll
    for (int nt = 0; nt < 4; ++nt) {
        float bias = bo[nt0 + nt * 16 + l16];
        #pragma unroll
        for (int r = 0; r < 4; ++r) {
            int m = 16 * w + quad * 4 + r;
            Cs[m * 65 + nt * 16 + l16] = acc[0][nt][r] + bias;
        }
    }
    __syncthreads();
    #pragma unroll
    for (int p = 0; p < 16; ++p) {
        int cl = (t >> 6) + 4 * p;
        int nl = t & 63;
        out[(size_t)(b * CC + nt0 + cl) * NN + n0 + nl] = Cs[nl * 65 + cl];
    }
}

// ---------------------------------------------------------------------------
extern "C" void kernel_launch(void* const* d_in, const int* in_sizes, int n_in,
                              void* d_out, int out_size, void* d_ws, size_t ws_size,
                              hipStream_t stream) {
    const float* q      = (const float*)d_in[0];
    const float* k      = (const float*)d_in[1];
    const float* v      = (const float*)d_in[2];
    const float* coarse = (const float*)d_in[3];
    const float* Wq     = (const float*)d_in[4];
    const float* bq     = (const float*)d_in[5];
    const float* Wk     = (const float*)d_in[6];
    const float* bk     = (const float*)d_in[7];
    const float* Wv     = (const float*)d_in[8];
    const float* bv     = (const float*)d_in[9];
    const float* Wo     = (const float*)d_in[10];
    const float* bo     = (const float*)d_in[11];

    char* ws = (char*)d_ws;
    const size_t MB4 = (size_t)BB * NN * CC * 2;     // 4 MiB (bf16 B*N*C)
    short* qt = (short*)(ws);                        // dead after proj -> xo
    short* kt = (short*)(ws + MB4);
    short* vt = (short*)(ws + 2 * MB4);
    short* qp = (short*)(ws + 3 * MB4);
    short* kp = (short*)(ws + 4 * MB4);
    short* vp = (short*)(ws + 5 * MB4);
    short* Wt = (short*)(ws + 6 * MB4);              // 4 x 128 KiB
    int* fidx = (int*)(ws + 6 * MB4 + 4 * (size_t)CC * CC * 2);
    short* xo = qt;                                  // alias (qt dead by then)

    prep_kernel<<<dim3(64, 4, 7), 256, 0, stream>>>(q, k, v, Wq, Wk, Wv, Wo,
                                                    coarse, qt, kt, vt, Wt, fidx);
    proj_gemm<<<dim3(64, 4, 3), 256, 0, stream>>>(qt, kt, vt, Wt, bq, bk, bv,
                                                  qp, kp, vp);
    attn_kernel<<<dim3(NLOW, BB), 256, 0, stream>>>(qp, kp, vp, fidx, xo);
    outproj_gemm<<<dim3(128, 4), 256, 0, stream>>>(xo, Wt + 3 * CC * CC, bo,
                                                   (float*)d_out);
}

// Round 6
// 120.055 us; speedup vs baseline: 1.5552x; 1.0419x over previous
//
#include <hip/hip_runtime.h>
#include <hip/hip_bf16.h>
#include <cstddef>

#define BB 2
#define CC 256
#define HH 64
#define WW 64
#define NN 4096      // H*W
#define NH 8
#define HD 32
#define NLOW 256     // (H/4)*(W/4)
#define KLEN 32      // K_SAMPLES * RATIO^2

typedef __attribute__((ext_vector_type(8))) short short8;
typedef __attribute__((ext_vector_type(4))) float float4v;

__device__ __forceinline__ float b2f(short s) {
    union { unsigned u; float f; } x;
    x.u = ((unsigned)(unsigned short)s) << 16;
    return x.f;
}
__device__ __forceinline__ short f2b(float f) {
    __hip_bfloat16 h = __float2bfloat16(f);  // RNE
    return __builtin_bit_cast(short, h);
}

// ---------------------------------------------------------------------------
// Prep kernel: z<6 -> feature transpose tiles; z==6 -> weight transposes (64
// jobs) + top-2 reduction (128 jobs).
// ---------------------------------------------------------------------------
__device__ __forceinline__ void trans_tile(const float* __restrict__ src, size_t soff,
                                           int sld, short* __restrict__ dst,
                                           size_t doff, int dld) {
    __shared__ float tile[64 * 65];
    const int t = threadIdx.x;
    #pragma unroll
    for (int p = 0; p < 4; ++p) {
        int r  = p * 16 + (t >> 4);
        int c4 = (t & 15) * 4;
        float4v v = *(const float4v*)&src[soff + (size_t)r * sld + c4];
        tile[r * 65 + c4 + 0] = v[0];
        tile[r * 65 + c4 + 1] = v[1];
        tile[r * 65 + c4 + 2] = v[2];
        tile[r * 65 + c4 + 3] = v[3];
    }
    __syncthreads();
    #pragma unroll
    for (int p = 0; p < 2; ++p) {
        int n  = p * 32 + (t >> 3);      // dst row (src col)
        int c0 = (t & 7) * 8;            // dst col chunk (src rows)
        short8 o;
        #pragma unroll
        for (int j = 0; j < 8; ++j) o[j] = f2b(tile[(c0 + j) * 65 + n]);
        *(short8*)&dst[doff + (size_t)n * dld + c0] = o;
    }
}

__global__ __launch_bounds__(256) void prep_kernel(
    const float* __restrict__ q, const float* __restrict__ k,
    const float* __restrict__ v, const float* __restrict__ Wq,
    const float* __restrict__ Wk, const float* __restrict__ Wv,
    const float* __restrict__ Wo, const float* __restrict__ coarse,
    short* __restrict__ qt, short* __restrict__ kt, short* __restrict__ vt,
    short* __restrict__ Wt, int* __restrict__ fidx) {
    const int z = blockIdx.z;
    if (z < 6) {                                   // feature transposes
        const float* src = (z < 2) ? q : (z < 4) ? k : v;
        short* dst       = (z < 2) ? qt : (z < 4) ? kt : vt;
        const int b = z & 1;
        const int n0 = blockIdx.x * 64, c0 = blockIdx.y * 64;
        trans_tile(src, (size_t)b * CC * NN + (size_t)c0 * NN + n0, NN,
                   dst, ((size_t)b * NN + n0) * CC + c0, CC);
        return;
    }
    const int id = blockIdx.y * 64 + blockIdx.x;   // 0..255
    if (id < 64) {                                 // weight transposes
        const int wz = id >> 4, tile = id & 15;
        const float* src = (wz == 0) ? Wq : (wz == 1) ? Wk : (wz == 2) ? Wv : Wo;
        short* dst = Wt + (size_t)wz * CC * CC;
        const int co0 = (tile >> 2) * 64, ci0 = (tile & 3) * 64;
        trans_tile(src, (size_t)ci0 * CC + co0, CC,
                   dst, (size_t)co0 * CC + ci0, CC);
        return;
    }
    if (id >= 192) return;
    // top-2: 4 rows per block, one wave per row
    const int w = threadIdx.x >> 6, l = threadIdx.x & 63;
    const int row = (id - 64) * 4 + w;             // 0..511 = b*NLOW+low
    const float* r = coarse + (size_t)row * NLOW;
    float4v x = *(const float4v*)&r[l * 4];
    const int base = l * 4;
    float v1 = x[0]; int i1 = base;
    float v2 = x[1]; int i2 = base + 1;
    if (v2 > v1) { float tv = v1; v1 = v2; v2 = tv; int ti = i1; i1 = i2; i2 = ti; }
    #pragma unroll
    for (int j = 2; j < 4; ++j) {
        float e = x[j]; int ei = base + j;
        if (e > v1)      { v2 = v1; i2 = i1; v1 = e; i1 = ei; }
        else if (e > v2) { v2 = e;  i2 = ei; }
    }
    #pragma unroll
    for (int off = 1; off < 64; off <<= 1) {
        float ov1 = __shfl_xor(v1, off), ov2 = __shfl_xor(v2, off);
        int   oi1 = __shfl_xor(i1, off), oi2 = __shfl_xor(i2, off);
        bool aw = (v1 > ov1) || (v1 == ov1 && i1 < oi1);
        float nv1 = aw ? v1 : ov1;  int ni1 = aw ? i1 : oi1;
        float c1v = aw ? ov1 : v1;  int c1i = aw ? oi1 : i1;   // loser of firsts
        float c2v = aw ? v2 : ov2;  int c2i = aw ? i2 : oi2;   // winner's 2nd
        bool bw = (c1v > c2v) || (c1v == c2v && c1i < c2i);
        v1 = nv1; i1 = ni1;
        v2 = bw ? c1v : c2v; i2 = bw ? c1i : c2i;
    }
    if (l < 32) {
        int s = l >> 4, jj = l & 15;
        int idx = s ? i2 : i1;
        int rr = jj >> 2, cc2 = jj & 3;
        fidx[(size_t)row * KLEN + l] =
            ((idx >> 4) * 4 + rr) * WW + (idx & 15) * 4 + cc2;
    }
}

// ---------------------------------------------------------------------------
// GEMM core, MT m-subtiles of 64 (tile = 64*MT x 64), BK=64.  XOR-swizzled
// LDS chunks: logical (m, chunk c) at physical chunk m*8 + (c ^ (m&7)).
// ---------------------------------------------------------------------------
template <int MT>
__device__ __forceinline__ void gemm_core(
    const short* __restrict__ A, int am0, const short* __restrict__ Bt, int bn0,
    short* As, short* Bs, float4v acc[MT][4]) {
    const int t = threadIdx.x;
    const int w = t >> 6, lane = t & 63;
    const int l16 = lane & 15, quad = lane >> 4;
    for (int k0 = 0; k0 < CC; k0 += 64) {
        __syncthreads();
        #pragma unroll
        for (int g = 0; g < 2 * MT; ++g) {
            int p = (w * 2 * MT + g) * 64 + lane;     // physical chunk
            int m = p >> 3;
            int cl8 = (((p & 7) ^ (m & 7)) << 3);     // logical k-offset (elems)
            *(short8*)((char*)As + (size_t)p * 16) =
                *(const short8*)(A + (size_t)(am0 + m) * CC + k0 + cl8);
        }
        #pragma unroll
        for (int g = 0; g < 2; ++g) {
            int p = (w * 2 + g) * 64 + lane;
            int m = p >> 3;
            int cl8 = (((p & 7) ^ (m & 7)) << 3);
            *(short8*)((char*)Bs + (size_t)p * 16) =
                *(const short8*)(Bt + (size_t)(bn0 + m) * CC + k0 + cl8);
        }
        __syncthreads();
        #pragma unroll
        for (int s = 0; s < 2; ++s) {
            short8 bf[4];
            #pragma unroll
            for (int nt = 0; nt < 4; ++nt) {
                const int Rb = nt * 16 + l16;
                bf[nt] = *(const short8*)((const char*)Bs + Rb * 128 +
                                          (((s * 4 + quad) ^ (Rb & 7)) << 4));
            }
            #pragma unroll
            for (int mt = 0; mt < MT; ++mt) {
                const int Ra = mt * 64 + 16 * w + l16;
                short8 af = *(const short8*)((const char*)As + Ra * 128 +
                                             (((s * 4 + quad) ^ (Ra & 7)) << 4));
                #pragma unroll
                for (int nt = 0; nt < 4; ++nt)
                    acc[mt][nt] = __builtin_amdgcn_mfma_f32_16x16x32_bf16(
                        af, bf[nt], acc[mt][nt], 0, 0, 0);
            }
        }
    }
}

// Kernel: fused q/k/v projections, 128x64 tiles (bf16 in/out row-major)
__global__ __launch_bounds__(256) void proj_gemm(
    const short* __restrict__ qt, const short* __restrict__ kt,
    const short* __restrict__ vt, const short* __restrict__ Wt,
    const float* __restrict__ bq, const float* __restrict__ bk,
    const float* __restrict__ bv,
    short* __restrict__ qp, short* __restrict__ kp, short* __restrict__ vp) {
    const int which = blockIdx.z;
    const short* A  = which == 0 ? qt : which == 1 ? kt : vt;
    const short* B  = Wt + (size_t)which * CC * CC;
    const float* bias = which == 0 ? bq : which == 1 ? bk : bv;
    short* outp     = which == 0 ? qp : which == 1 ? kp : vp;
    const int am0 = blockIdx.x * 128;       // row tile in (B*N) space
    const int nt0 = blockIdx.y * 64;

    __shared__ short As[128 * 64];
    __shared__ short Bs[64 * 64];
    float4v acc[2][4];
    #pragma unroll
    for (int i = 0; i < 2; ++i)
        #pragma unroll
        for (int j = 0; j < 4; ++j) acc[i][j] = (float4v)(0.f);

    gemm_core<2>(A, am0, B, nt0, As, Bs, acc);

    const int t = threadIdx.x;
    const int w = t >> 6, lane = t & 63;
    const int l16 = lane & 15, quad = lane >> 4;
    #pragma unroll
    for (int mt = 0; mt < 2; ++mt)
        #pragma unroll
        for (int nt = 0; nt < 4; ++nt) {
            int col = nt0 + nt * 16 + l16;
            float bv_ = bias[col];
            #pragma unroll
            for (int r = 0; r < 4; ++r) {
                int m = am0 + mt * 64 + 16 * w + quad * 4 + r;
                outp[(size_t)m * CC + col] = f2b(acc[mt][nt][r] + bv_);
            }
        }
}

// ---------------------------------------------------------------------------
// Fused sparse attention + output projection.  One block (256 thr) per
// (b,low).  Attention: thread = (qi, h, dh), 32 keys in LDS.  Then the
// 16x256 x-tile goes to LDS (bf16, XOR-swizzled) and x @ Wo^T runs on MFMA
// with B-fragments streamed from global (Wo^T is L2-resident); fp32 (B,C,N)
// stores: each lane holds 4 consecutive n per co -> float4 stores.
// ---------------------------------------------------------------------------
#define KSTR 264   // shorts; 528 B rows (16B aligned)

__global__ __launch_bounds__(256) void attn_out_kernel(
    const short* __restrict__ qp, const short* __restrict__ kp,
    const short* __restrict__ vp, const int* __restrict__ fidx,
    const short* __restrict__ Wto, const float* __restrict__ bo,
    float* __restrict__ out) {
    const int low = blockIdx.x, b = blockIdx.y;
    const int t = threadIdx.x;

    __shared__ short Ks[32 * KSTR];
    __shared__ short Vs[32 * KSTR];
    __shared__ short Xs[16 * 32 * 8];   // 16 rows x 32 chunks(8 bf16), swizzled
    __shared__ int idx_s[KLEN];

    if (t < KLEN) {
        int idx = fidx[(size_t)(b * NLOW + low) * KLEN + t];
        idx_s[t] = idx < 0 ? 0 : (idx > NN - 1 ? NN - 1 : idx);
    }
    __syncthreads();

    const int* kpi = (const int*)kp;
    const int* vpi = (const int*)vp;
    const int half = t >> 7, col = t & 127;
    for (int j = 0; j < KLEN; j += 2) {
        int key = j + half;
        size_t base = (size_t)(b * NN + idx_s[key]) * (CC / 2);
        ((int*)&Ks[key * KSTR])[col] = kpi[base + col];
        ((int*)&Vs[key * KSTR])[col] = vpi[base + col];
    }
    __syncthreads();

    const int qi = t >> 4, h = (t >> 1) & 7, dh = t & 1;
    const int n = low * 16 + qi;             // low == n>>4 (repeat semantics)
    const short* qrow = qp + (size_t)(b * NN + n) * CC + h * HD + dh * 16;

    float qv[16];
    #pragma unroll
    for (int c = 0; c < 2; ++c) {
        short8 v = *(const short8*)&qrow[c * 8];
        #pragma unroll
        for (int e = 0; e < 8; ++e) qv[c * 8 + e] = b2f(v[e]);
    }

    const float scale = 0.17677669529663687f;   // 32^-0.5
    float sc[KLEN];
    for (int j = 0; j < KLEN; ++j) {
        const short* kr = &Ks[j * KSTR + h * HD + dh * 16];
        float s = 0.f;
        #pragma unroll
        for (int c = 0; c < 2; ++c) {
            short8 v = *(const short8*)&kr[c * 8];
            #pragma unroll
            for (int e = 0; e < 8; ++e) s += qv[c * 8 + e] * b2f(v[e]);
        }
        sc[j] = s;
    }
    float mx = -1e30f;
    #pragma unroll
    for (int j = 0; j < KLEN; ++j) {
        sc[j] = (sc[j] + __shfl_xor(sc[j], 1)) * scale;   // combine halves
        mx = fmaxf(mx, sc[j]);
    }
    float denom = 0.f;
    #pragma unroll
    for (int j = 0; j < KLEN; ++j) { sc[j] = __expf(sc[j] - mx); denom += sc[j]; }
    const float inv = 1.f / denom;

    float ov[16];
    #pragma unroll
    for (int d = 0; d < 16; ++d) ov[d] = 0.f;
    for (int j = 0; j < KLEN; ++j) {
        float p = sc[j] * inv;
        const short* vr = &Vs[j * KSTR + h * HD + dh * 16];
        #pragma unroll
        for (int c = 0; c < 2; ++c) {
            short8 v = *(const short8*)&vr[c * 8];
            #pragma unroll
            for (int e = 0; e < 8; ++e) ov[c * 8 + e] += p * b2f(v[e]);
        }
    }

    // x-tile (16 x 256) -> LDS bf16, XOR-swizzled: chunk (m, c) at
    // m*32 + (c & ~7) + ((c & 7) ^ (m & 7)).
    #pragma unroll
    for (int c = 0; c < 2; ++c) {
        int lc = h * 4 + dh * 2 + c;              // logical chunk 0..31
        int p = qi * 32 + (lc & ~7) + ((lc & 7) ^ (qi & 7));
        short8 v;
        #pragma unroll
        for (int e = 0; e < 8; ++e) v[e] = f2b(ov[c * 8 + e]);
        *(short8*)((char*)Xs + (size_t)p * 16) = v;
    }
    __syncthreads();

    // out-proj: wave w covers co = w*64 .. w*64+63.  8 k-steps x 4 co-subtiles.
    const int w = t >> 6, lane = t & 63;
    const int l16 = lane & 15, quad = lane >> 4;
    float4v acc[4];
    #pragma unroll
    for (int i = 0; i < 4; ++i) acc[i] = (float4v)(0.f);

    #pragma unroll
    for (int s = 0; s < 8; ++s) {
        int lc = s * 4 + quad;                    // logical chunk
        int p = l16 * 32 + (lc & ~7) + ((lc & 7) ^ (l16 & 7));
        short8 af = *(const short8*)((const char*)Xs + (size_t)p * 16);
        #pragma unroll
        for (int nt = 0; nt < 4; ++nt) {
            int co = w * 64 + nt * 16 + l16;
            short8 bf = *(const short8*)(Wto + (size_t)co * CC + s * 32 + quad * 8);
            acc[nt] = __builtin_amdgcn_mfma_f32_16x16x32_bf16(af, bf, acc[nt], 0, 0, 0);
        }
    }

    const int nbase = low * 16 + quad * 4;        // 4 consecutive n per lane
    #pragma unroll
    for (int nt = 0; nt < 4; ++nt) {
        int c = w * 64 + nt * 16 + l16;
        float bias = bo[c];
        float4v o;
        #pragma unroll
        for (int r = 0; r < 4; ++r) o[r] = acc[nt][r] + bias;
        *(float4v*)&out[(size_t)(b * CC + c) * NN + nbase] = o;
    }
}

// ---------------------------------------------------------------------------
extern "C" void kernel_launch(void* const* d_in, const int* in_sizes, int n_in,
                              void* d_out, int out_size, void* d_ws, size_t ws_size,
                              hipStream_t stream) {
    const float* q      = (const float*)d_in[0];
    const float* k      = (const float*)d_in[1];
    const float* v      = (const float*)d_in[2];
    const float* coarse = (const float*)d_in[3];
    const float* Wq     = (const float*)d_in[4];
    const float* bq     = (const float*)d_in[5];
    const float* Wk     = (const float*)d_in[6];
    const float* bk     = (const float*)d_in[7];
    const float* Wv     = (const float*)d_in[8];
    const float* bv     = (const float*)d_in[9];
    const float* Wo     = (const float*)d_in[10];
    const float* bo     = (const float*)d_in[11];

    char* ws = (char*)d_ws;
    const size_t MB4 = (size_t)BB * NN * CC * 2;     // 4 MiB (bf16 B*N*C)
    short* qt = (short*)(ws);
    short* kt = (short*)(ws + MB4);
    short* vt = (short*)(ws + 2 * MB4);
    short* qp = (short*)(ws + 3 * MB4);
    short* kp = (short*)(ws + 4 * MB4);
    short* vp = (short*)(ws + 5 * MB4);
    short* Wt = (short*)(ws + 6 * MB4);              // 4 x 128 KiB
    int* fidx = (int*)(ws + 6 * MB4 + 4 * (size_t)CC * CC * 2);

    prep_kernel<<<dim3(64, 4, 7), 256, 0, stream>>>(q, k, v, Wq, Wk, Wv, Wo,
                                                    coarse, qt, kt, vt, Wt, fidx);
    proj_gemm<<<dim3(64, 4, 3), 256, 0, stream>>>(qt, kt, vt, Wt, bq, bk, bv,
                                                  qp, kp, vp);
    attn_out_kernel<<<dim3(NLOW, BB), 256, 0, stream>>>(qp, kp, vp, fidx,
                                                        Wt + 3 * CC * CC, bo,
                                                        (float*)d_out);
}